// Round 4
// baseline (666.885 us; speedup 1.0000x reference)
//
#include <hip/hip_runtime.h>
#include <math.h>

#define C_DIM 256
#define N_CODE 1024
#define T_TOK 32768
#define MARGIN 8.0e-3f
#define REC_CAP 4096

typedef _Float16 half8 __attribute__((ext_vector_type(8)));
typedef float f32x4 __attribute__((ext_vector_type(4)));

// ---------------------------------------------------------------------------
// ws layout (floats):
//   [0, 1024)       esq
//   [1024, 2048)    counts   (zeroed by memset)
//   [2048]          sse      (zeroed by memset)
//   [3072, 35840)   zsq
//   [35840, 68608)  idx (int)
// d_out scratch (fully rewritten by k_out/k_final afterwards; half-unit ptr
// arithmetic: z16 ends at half-offset 8388608 = byte 16.78MB, cb16 ends at
// 17.3MB, both inside outq's 33.5MB):
//   z16  = (_Float16*)d_out            [32768][256] fp16
//   cb16 = (_Float16*)d_out + 8388608  [1024][256]  fp16
// ---------------------------------------------------------------------------

// esq + fp16 codebook. esq summation-order error ~6e-11 vs the 1.5e-5
// rounding-boundary scale -> insensitive, any order OK.
__global__ __launch_bounds__(256) void k_esqcb(const float* __restrict__ cb,
    float* __restrict__ esq, _Float16* __restrict__ cb16)
{
    int n = blockIdx.x * 256 + threadIdx.x;
    const float* row = cb + (size_t)n * C_DIM;
    float s = 0.0f;
    for (int k = 0; k < C_DIM; k += 8) {
        float4 a = *(const float4*)(row + k);
        float4 b = *(const float4*)(row + k + 4);
        s = fmaf(a.x, a.x, s); s = fmaf(a.y, a.y, s);
        s = fmaf(a.z, a.z, s); s = fmaf(a.w, a.w, s);
        s = fmaf(b.x, b.x, s); s = fmaf(b.y, b.y, s);
        s = fmaf(b.z, b.z, s); s = fmaf(b.w, b.w, s);
        _Float16 p[8];
        p[0] = (_Float16)a.x; p[1] = (_Float16)a.y; p[2] = (_Float16)a.z; p[3] = (_Float16)a.w;
        p[4] = (_Float16)b.x; p[5] = (_Float16)b.y; p[6] = (_Float16)b.z; p[7] = (_Float16)b.w;
        *(half8*)(cb16 + (size_t)n * C_DIM + k) = *(half8*)p;
    }
    esq[n] = s;
}

// Transpose z [B,C,H,W] -> z16 [t][c] fp16 (token-major), fused zsq that
// bit-replicates the hypothesized XLA row-reduce (HYPOTHESIS A): virtual
// lane i of 64 owns contiguous float4 chunk c=[4i,4i+4) (sequential mul,add,
// NO contraction), then shfl-down tree offsets 32,16,8,4,2,1.
// Virtual lane decomposition: i = 16*cc + 4*part + u.
// If first bench shows ~0.1-0.5% index mismatches, swap to HYPOTHESIS B
// (strided: lane i owns i, i+64, i+128, i+192) -- isolated to this kernel.
__global__ __launch_bounds__(256) void k_prep(const float* __restrict__ z,
    _Float16* __restrict__ z16, float* __restrict__ zsq)
{
#pragma clang fp contract(off)
    __shared__ float tile[64 * 68];   // stride 68: float4-aligned (68%4==0)
    int tid = threadIdx.x;
    int t0 = blockIdx.x * 64;
    int b = t0 >> 10, hw0 = t0 & 1023;
    int t = tid >> 2, part = tid & 3;
    float P[4][4];
    #pragma unroll
    for (int cc = 0; cc < 4; ++cc)
        #pragma unroll
        for (int u = 0; u < 4; ++u) P[cc][u] = 0.0f;

    #pragma unroll            // force static P indexing (rule #20)
    for (int cc = 0; cc < 4; ++cc) {
        int c0 = cc * 64;
        __syncthreads();
        #pragma unroll
        for (int q = 0; q < 4; ++q) {
            int fi = tid + 256 * q;
            int c = fi >> 4, h4 = (fi & 15) * 4;
            float4 v = *(const float4*)(z + ((size_t)(b * C_DIM + c0 + c)) * 1024 + hw0 + h4);
            *(float4*)&tile[c * 68 + h4] = v;   // offset %4 == 0 -> aligned b128
        }
        __syncthreads();
        _Float16 pack[16];
        #pragma unroll
        for (int j = 0; j < 16; ++j) {
            float v = tile[(part * 16 + j) * 68 + t];
            float m = v * v;                 // separate rounding (contract off)
            P[cc][j >> 2] = P[cc][j >> 2] + m;
            pack[j] = (_Float16)v;
        }
        *(half8*)(z16 + (size_t)(t0 + t) * C_DIM + c0 + part * 16)     = *(half8*)&pack[0];
        *(half8*)(z16 + (size_t)(t0 + t) * C_DIM + c0 + part * 16 + 8) = *(half8*)&pack[8];
    }
    // tree: offs 32 (cc+2), 16 (cc+1), 8 (part^2), 4 (part^1), 2 (u+2), 1 (u+1)
    float Bv[4], Cv[4], Dv[4];
    #pragma unroll
    for (int u = 0; u < 4; ++u) {
        float A0 = P[0][u] + P[2][u];
        float A1 = P[1][u] + P[3][u];
        Bv[u] = A0 + A1;
    }
    #pragma unroll
    for (int u = 0; u < 4; ++u) Cv[u] = Bv[u] + __shfl_xor(Bv[u], 2, 64);
    #pragma unroll
    for (int u = 0; u < 4; ++u) Dv[u] = Cv[u] + __shfl_xor(Cv[u], 1, 64);
    float E0 = Dv[0] + Dv[2];
    float E1 = Dv[1] + Dv[3];
    float F = E0 + E1;
    if (part == 0) zsq[t0 + t] = F;
}

// MFMA approximate scoring + margin candidate capture + exact fp32 rescore.
// Block: 128 tokens, 4 waves as 2x2 (token-half wr, code-half wc) per
// 128-code chunk; 8 chunks cover N=1024. Wave tile 64x64 via 4x4 frags of
// mfma_f32_16x16x32_f16 (C/D: col=lane&15, row=(lane>>4)*4+reg).
// Fragments load directly from global (L1/L2-resident).
// Rescore: 4 passes, each staging a 32-token fp32 z tile in LDS (fixes the
// scattered channel-major z gather), candidates filtered by token group.
__global__ __launch_bounds__(256, 2) void k_score(
    const _Float16* __restrict__ z16, const _Float16* __restrict__ cb16,
    const float* __restrict__ esq, const float* __restrict__ zsq,
    const float* __restrict__ z, const float* __restrict__ cb,
    int* __restrict__ idxout)
{
    __shared__ float zl[32][260];          // 33.3KB, float4-aligned stride
    __shared__ unsigned int recs[REC_CAP]; // 16KB
    __shared__ unsigned long long keys[128];
    __shared__ int cnt;

    int tid = threadIdx.x;
    int t0 = blockIdx.x * 128;
    int b = t0 >> 10, hw0 = t0 & 1023;
    int lane = tid & 63;
    int w = tid >> 6;
    int wr = w >> 1, wc = w & 1;
    int l15 = lane & 15, g4 = lane >> 4;

    if (tid < 128) keys[tid] = 0xFFFFFFFFFFFFFFFFULL;
    if (tid == 0) cnt = 0;
    __syncthreads();

    float runm[4][4];
    #pragma unroll
    for (int i = 0; i < 4; ++i)
        #pragma unroll
        for (int r = 0; r < 4; ++r) runm[i][r] = INFINITY;

    const _Float16* Abase = z16 + (size_t)(t0 + wr * 64 + l15) * C_DIM + g4 * 8;
    const _Float16* Bbase = cb16 + (size_t)(wc * 64 + l15) * C_DIM + g4 * 8;

    for (int chunk = 0; chunk < 8; ++chunk) {
        int n0 = chunk * 128;
        const _Float16* Bb = Bbase + (size_t)n0 * C_DIM;
        f32x4 acc[4][4];
        #pragma unroll
        for (int i = 0; i < 4; ++i)
            #pragma unroll
            for (int j = 0; j < 4; ++j) acc[i][j] = (f32x4){0.f, 0.f, 0.f, 0.f};

        float eq[4];
        #pragma unroll
        for (int j = 0; j < 4; ++j) eq[j] = esq[n0 + wc * 64 + j * 16 + l15];

        #pragma unroll
        for (int ks = 0; ks < 8; ++ks) {
            half8 af[4], bf[4];
            #pragma unroll
            for (int i = 0; i < 4; ++i)
                af[i] = *(const half8*)(Abase + (size_t)(i * 16) * C_DIM + ks * 32);
            #pragma unroll
            for (int j = 0; j < 4; ++j)
                bf[j] = *(const half8*)(Bb + (size_t)(j * 16) * C_DIM + ks * 32);
            #pragma unroll
            for (int i = 0; i < 4; ++i)
                #pragma unroll
                for (int j = 0; j < 4; ++j)
                    acc[i][j] = __builtin_amdgcn_mfma_f32_16x16x32_f16(af[i], bf[j], acc[i][j], 0, 0, 0);
        }
        // g = esq - 2*s; per-token min over this wave's 64 codes (butterfly
        // over the 16 lanes sharing g4); capture codes with g <= runmin + M.
        #pragma unroll
        for (int i = 0; i < 4; ++i) {
            #pragma unroll
            for (int r = 0; r < 4; ++r) {
                float g0 = eq[0] - 2.0f * acc[i][0][r];
                float g1 = eq[1] - 2.0f * acc[i][1][r];
                float g2 = eq[2] - 2.0f * acc[i][2][r];
                float g3 = eq[3] - 2.0f * acc[i][3][r];
                float m = fminf(fminf(g0, g1), fminf(g2, g3));
                float bm = m;
                bm = fminf(bm, __shfl_xor(bm, 1, 64));
                bm = fminf(bm, __shfl_xor(bm, 2, 64));
                bm = fminf(bm, __shfl_xor(bm, 4, 64));
                bm = fminf(bm, __shfl_xor(bm, 8, 64));
                float rm = fminf(runm[i][r], bm);
                runm[i][r] = rm;
                float thr = rm + MARGIN;
                if (m <= thr) {
                    int tl = wr * 64 + i * 16 + g4 * 4 + r;
                    int nb = n0 + wc * 64 + l15;
                    if (g0 <= thr) { int p = atomicAdd(&cnt, 1); if (p < REC_CAP) recs[p] = (unsigned)((tl << 10) | nb); }
                    if (g1 <= thr) { int p = atomicAdd(&cnt, 1); if (p < REC_CAP) recs[p] = (unsigned)((tl << 10) | (nb + 16)); }
                    if (g2 <= thr) { int p = atomicAdd(&cnt, 1); if (p < REC_CAP) recs[p] = (unsigned)((tl << 10) | (nb + 32)); }
                    if (g3 <= thr) { int p = atomicAdd(&cnt, 1); if (p < REC_CAP) recs[p] = (unsigned)((tl << 10) | (nb + 48)); }
                }
            }
        }
    }
    __syncthreads();
    int ncand = cnt; if (ncand > REC_CAP) ncand = REC_CAP;

    // Exact fp32 rescore (authority for final indices), 4 token-group passes.
    // d = fl(fl(zsq+esq) - 2*ze); packed u64 atomicMin -> lowest-index ties.
    for (int tg = 0; tg < 4; ++tg) {
        __syncthreads();
        // stage fp32 z tile for tokens [tg*32, tg*32+32): coalesced
        #pragma unroll 4
        for (int it = 0; it < 32; ++it) {
            int fi = tid + 256 * it;
            int tok = fi & 31, c = fi >> 5;
            zl[tok][c] = z[((size_t)(b * C_DIM + c)) * 1024 + hw0 + tg * 32 + tok];
        }
        __syncthreads();
        for (int r0 = w * 4; r0 < ncand; r0 += 16) {
            #pragma unroll
            for (int u = 0; u < 4; ++u) {
                int r = r0 + u;
                if (r >= ncand) break;            // wave-uniform
                unsigned rec = recs[r];           // broadcast read
                int tl = (int)(rec >> 10);
                if ((tl >> 5) != tg) continue;    // wave-uniform
                int nn = (int)(rec & 1023u);
                f32x4 zv = *(const f32x4*)&zl[tl & 31][lane * 4];
                f32x4 cv = *(const f32x4*)(cb + (size_t)nn * C_DIM + lane * 4);
                float s = zv[0] * cv[0];
                s = fmaf(zv[1], cv[1], s);
                s = fmaf(zv[2], cv[2], s);
                s = fmaf(zv[3], cv[3], s);
                #pragma unroll
                for (int mm = 1; mm < 64; mm <<= 1) s += __shfl_xor(s, mm, 64);
                float d = (zsq[t0 + tl] + esq[nn]) - 2.0f * s;
                unsigned long long key = ((unsigned long long)__float_as_uint(d) << 32) | (unsigned)nn;
                if (lane == 0) atomicMin(&keys[tl], key);
            }
        }
    }
    __syncthreads();
    if (tid < 128) idxout[t0 + tid] = (int)(keys[tid] & 1023ULL);
}

// Gather z_q, write z_q_st = fl(z + fl(z_q - z)), float indices, histogram, SSE.
__global__ __launch_bounds__(256) void k_out(
    const float* __restrict__ z, const float* __restrict__ cb,
    const int* __restrict__ idx, float* __restrict__ outq,
    float* __restrict__ outidx, float* __restrict__ counts,
    float* __restrict__ sse)
{
    __shared__ float rows[32][260];   // stride 260: float4-aligned
    __shared__ float red[4];
    int tid = threadIdx.x;
    int t0 = blockIdx.x * 32;
    int b = t0 >> 10, hw0 = t0 & 1023;
    {
        int tr = tid & 31, p = tid >> 5;   // tr in lane-low bits: 2/bank writes
        int n = idx[t0 + tr];
        const float* src = cb + (size_t)n * C_DIM + p * 32;
        #pragma unroll
        for (int q = 0; q < 8; ++q) {
            float4 v = *(const float4*)(src + q * 4);
            *(float4*)&rows[tr][p * 32 + q * 4] = v;   // aligned (offset%4==0)
        }
    }
    if (tid < 32) {
        int n = idx[t0 + tid];
        outidx[t0 + tid] = (float)n;
        atomicAdd(&counts[n], 1.0f);
    }
    __syncthreads();
    int tl = tid & 31, c4 = tid >> 5;
    float part = 0.0f;
    for (int cc = 0; cc < 32; ++cc) {
        int c = cc * 8 + c4;
        size_t off = ((size_t)(b * C_DIM + c)) * 1024 + hw0 + tl;
        float zv = z[off];
        float qv = rows[tl][c];
        float dd = qv - zv;        // fl(z_q - z)
        outq[off] = zv + dd;       // fl(z + fl(z_q - z))
        part = fmaf(dd, dd, part);
    }
    #pragma unroll
    for (int m = 1; m < 64; m <<= 1) part += __shfl_xor(part, m, 64);
    if ((tid & 63) == 0) red[tid >> 6] = part;
    __syncthreads();
    if (tid == 0) atomicAdd(sse, red[0] + red[1] + red[2] + red[3]);
}

__global__ __launch_bounds__(1024) void k_final(
    const float* __restrict__ counts, const float* __restrict__ sse,
    float* __restrict__ outsc)
{
    __shared__ float red[16];
    int tid = threadIdx.x;
    float p = counts[tid] * (1.0f / 32768.0f);   // /T exact (2^15)
    float term = p * logf(p + 1e-10f);
    #pragma unroll
    for (int m = 1; m < 64; m <<= 1) term += __shfl_xor(term, m, 64);
    if ((tid & 63) == 0) red[tid >> 6] = term;
    __syncthreads();
    if (tid == 0) {
        float s = 0.0f;
        #pragma unroll
        for (int i = 0; i < 16; ++i) s += red[i];
        float m = sse[0] / 8388608.0f;           // /2^23 exact
        outsc[0] = m + 0.25f * m;                // codebook + BETA*commitment
        outsc[1] = expf(-s);
    }
}

extern "C" void kernel_launch(void* const* d_in, const int* in_sizes, int n_in,
                              void* d_out, int out_size, void* d_ws, size_t ws_size,
                              hipStream_t stream) {
    const float* z  = (const float*)d_in[0];
    const float* cb = (const float*)d_in[1];
    float* wsf    = (float*)d_ws;
    float* esq    = wsf;
    float* counts = wsf + 1024;
    float* sse    = wsf + 2048;
    float* zsq    = wsf + 3072;
    int*   idx    = (int*)(wsf + 3072 + 32768);

    float* outq   = (float*)d_out;
    float* outidx = outq + 8388608;
    float* outsc  = outq + 8388608 + 32768;

    _Float16* z16  = (_Float16*)d_out;            // scratch, overwritten by k_out
    _Float16* cb16 = (_Float16*)d_out + 8388608;  // half-offset: byte 16.78MB, inside outq

    hipMemsetAsync(counts, 0, 1025 * sizeof(float), stream);  // counts + sse
    k_esqcb<<<4, 256, 0, stream>>>(cb, esq, cb16);
    k_prep<<<512, 256, 0, stream>>>(z, z16, zsq);
    k_score<<<256, 256, 0, stream>>>(z16, cb16, esq, zsq, z, cb, idx);
    k_out<<<1024, 256, 0, stream>>>(z, cb, idx, outq, outidx, counts, sse);
    k_final<<<1, 1024, 0, stream>>>(counts, sse, outsc);
}